// Round 5
// baseline (287.065 us; speedup 1.0000x reference)
//
#include <hip/hip_runtime.h>

#define BB 32
#define LL 1024
#define DD 64

typedef short bf16x8 __attribute__((ext_vector_type(8)));
typedef float f32x4 __attribute__((ext_vector_type(4)));

static __device__ __forceinline__ ushort f2bf(float x) {
  union { float f; unsigned u; } c; c.f = x;
  unsigned r = c.u + 0x7FFF + ((c.u >> 16) & 1);
  return (ushort)(r >> 16);
}

static __device__ __forceinline__ bf16x8 pack8(float4 a, float4 b) {
  union { ushort u[8]; bf16x8 v; } r;
  r.u[0] = f2bf(a.x); r.u[1] = f2bf(a.y); r.u[2] = f2bf(a.z); r.u[3] = f2bf(a.w);
  r.u[4] = f2bf(b.x); r.u[5] = f2bf(b.y); r.u[6] = f2bf(b.z); r.u[7] = f2bf(b.w);
  return r.v;
}

// Fused attention, f32 outputs. Block: 4 waves, one batch b, 16 query rows.
// Phase 1: waves split the 1024 keys 4x256 (S = QK^T/8, mask, softmax).
// attn_w stored f32 straight from registers; W also kept bf16 in LDS (Ws) as
// the phase-2 MFMA A operand. Phase 2: V transposed into LDS per 256-key
// quarter; wave wv owns d-cols [wv*16, wv*16+16) over the full k range.
__global__ __launch_bounds__(256) void attn(
    const float* __restrict__ Q, const float* __restrict__ K,
    const float* __restrict__ V, const int* __restrict__ vlen,
    float* __restrict__ outS, float* __restrict__ outW) {
  __shared__ __align__(16) ushort Ws[16][LL + 8];   // 33,024 B
  __shared__ __align__(16) ushort VT[DD][264];      // 33,792 B (one 256-key quarter)
  __shared__ float redm[4][16];
  __shared__ float reds[4][16];

  const int b = blockIdx.x >> 6;
  const int q0 = (blockIdx.x & 63) << 4;
  const int tid = threadIdx.x;
  const int wv = tid >> 6, lane = tid & 63;
  const int quad = lane >> 4, n16 = lane & 15;
  const int vl = vlen[b];

  // A-frags from Q (f32 -> bf16): A[m = n16][k = quad*8+j], second mfma k+32
  const float* Qp = Q + (size_t)(b * LL + q0 + n16) * DD + quad * 8;
  bf16x8 a0 = pack8(*(const float4*)Qp, *(const float4*)(Qp + 4));
  bf16x8 a1 = pack8(*(const float4*)(Qp + 32), *(const float4*)(Qp + 36));

  const float* Kb = K + (size_t)b * LL * DD;
  const int kb = wv * 256 + n16;  // this lane's key column base

  // ---- Phase 1: scores, 16 key-tiles of 16 per wave, K converted inline ----
  f32x4 acc[16];
#pragma unroll
  for (int t = 0; t < 16; ++t) {
    const float* Kp = Kb + (size_t)(kb + t * 16) * DD + quad * 8;
    bf16x8 b0 = pack8(*(const float4*)Kp, *(const float4*)(Kp + 4));
    bf16x8 b1 = pack8(*(const float4*)(Kp + 32), *(const float4*)(Kp + 36));
    f32x4 c = {0.f, 0.f, 0.f, 0.f};
    c = __builtin_amdgcn_mfma_f32_16x16x32_bf16(a0, b0, c, 0, 0, 0);
    c = __builtin_amdgcn_mfma_f32_16x16x32_bf16(a1, b1, c, 0, 0, 0);
    acc[t] = c;
  }

  // scale + mask + per-lane row maxes (lane holds rows quad*4+r, col kb+t*16)
  float pm[4] = {-3.0e38f, -3.0e38f, -3.0e38f, -3.0e38f};
#pragma unroll
  for (int t = 0; t < 16; ++t) {
    const bool valid = (kb + t * 16) < vl;
#pragma unroll
    for (int r = 0; r < 4; ++r) {
      float v = valid ? acc[t][r] * 0.125f : -1.0e6f;
      acc[t][r] = v;
      pm[r] = fmaxf(pm[r], v);
    }
  }
#pragma unroll
  for (int off = 1; off < 16; off <<= 1) {
#pragma unroll
    for (int r = 0; r < 4; ++r) pm[r] = fmaxf(pm[r], __shfl_xor(pm[r], off));
  }
  if (n16 == 0) {
#pragma unroll
    for (int r = 0; r < 4; ++r) redm[wv][quad * 4 + r] = pm[r];
  }
  __syncthreads();
  float gm[4];
#pragma unroll
  for (int r = 0; r < 4; ++r) {
    int row = quad * 4 + r;
    gm[r] = fmaxf(fmaxf(redm[0][row], redm[1][row]),
                  fmaxf(redm[2][row], redm[3][row]));
  }
  float ps[4] = {0.f, 0.f, 0.f, 0.f};
#pragma unroll
  for (int t = 0; t < 16; ++t) {
#pragma unroll
    for (int r = 0; r < 4; ++r) {
      float e = __expf(acc[t][r] - gm[r]);  // masked: exp(-1e6 - gm) == 0
      acc[t][r] = e;
      ps[r] += e;
    }
  }
#pragma unroll
  for (int off = 1; off < 16; off <<= 1) {
#pragma unroll
    for (int r = 0; r < 4; ++r) ps[r] += __shfl_xor(ps[r], off);
  }
  if (n16 == 0) {
#pragma unroll
    for (int r = 0; r < 4; ++r) reds[wv][quad * 4 + r] = ps[r];
  }
  __syncthreads();
  float inv[4];
#pragma unroll
  for (int r = 0; r < 4; ++r) {
    int row = quad * 4 + r;
    inv[r] = 1.0f / (reds[0][row] + reds[1][row] + reds[2][row] + reds[3][row]);
  }

  // ---- attn_w: f32 direct from registers; bf16 copy into Ws for phase 2 ----
  {
    float* dstW = outW + (size_t)b * LL * LL + (size_t)q0 * LL;
#pragma unroll
    for (int t = 0; t < 16; ++t) {
#pragma unroll
      for (int r = 0; r < 4; ++r) {
        float w = acc[t][r] * inv[r];
        dstW[(size_t)(quad * 4 + r) * LL + kb + t * 16] = w;  // 4x64B segments/store
        Ws[quad * 4 + r][kb + t * 16] = f2bf(w);
      }
    }
  }
  __syncthreads();

  // ---- Phase 2: O = W * V. 4 quarters of 256 keys; V transposed into LDS;
  //      wave wv computes d-cols [wv*16, wv*16+16) over all k. ----
  f32x4 o = {0.f, 0.f, 0.f, 0.f};
  const float* Vb = V + (size_t)b * LL * DD;
  for (int h = 0; h < 4; ++h) {
    __syncthreads();  // protect VT from previous quarter's readers
#pragma unroll
    for (int i = 0; i < 16; ++i) {
      int idx = (i * 256 + tid) * 4;  // 0..16383 over (kk, d)
      int kk = idx >> 6, d0 = idx & 63;
      float4 v = *(const float4*)(Vb + (size_t)(h * 256 + kk) * DD + d0);
      VT[d0 + 0][kk] = f2bf(v.x);
      VT[d0 + 1][kk] = f2bf(v.y);
      VT[d0 + 2][kk] = f2bf(v.z);
      VT[d0 + 3][kk] = f2bf(v.w);
    }
    __syncthreads();
#pragma unroll
    for (int ks = 0; ks < 8; ++ks) {
      int kl = ks * 32 + quad * 8;
      bf16x8 af = *(const bf16x8*)(&Ws[n16][h * 256 + kl]);
      bf16x8 bv = *(const bf16x8*)(&VT[wv * 16 + n16][kl]);
      o = __builtin_amdgcn_mfma_f32_16x16x32_bf16(af, bv, o, 0, 0, 0);
    }
  }
  // store O (f32): rows quad*4+r, col d = wv*16 + n16
#pragma unroll
  for (int r = 0; r < 4; ++r) {
    outS[(size_t)(b * LL + q0 + quad * 4 + r) * DD + wv * 16 + n16] = o[r];
  }
}

extern "C" void kernel_launch(void* const* d_in, const int* in_sizes, int n_in,
                              void* d_out, int out_size, void* d_ws, size_t ws_size,
                              hipStream_t stream) {
  const float* Q = (const float*)d_in[0];
  const float* K = (const float*)d_in[1];
  const float* V = (const float*)d_in[2];
  const int* vl = (const int*)d_in[3];
  float* outS = (float*)d_out;                 // attn_score [32,1024,64] f32
  float* outW = outS + (size_t)BB * LL * DD;   // attn_w     [32,1024,1024] f32
  (void)d_ws; (void)ws_size;

  attn<<<dim3(BB * 64), 256, 0, stream>>>(Q, K, V, vl, outS, outW);
}

// Round 6
// 218.462 us; speedup vs baseline: 1.3140x; 1.3140x over previous
//
#include <hip/hip_runtime.h>

#define BB 32
#define LL 1024
#define DD 64

typedef short bf16x8 __attribute__((ext_vector_type(8)));
typedef float f32x4 __attribute__((ext_vector_type(4)));

static __device__ __forceinline__ ushort f2bf(float x) {
  union { float f; unsigned u; } c; c.f = x;
  unsigned r = c.u + 0x7FFF + ((c.u >> 16) & 1);
  return (ushort)(r >> 16);
}

static __device__ __forceinline__ bf16x8 pack8(float4 a, float4 b) {
  union { ushort u[8]; bf16x8 v; } r;
  r.u[0] = f2bf(a.x); r.u[1] = f2bf(a.y); r.u[2] = f2bf(a.z); r.u[3] = f2bf(a.w);
  r.u[4] = f2bf(b.x); r.u[5] = f2bf(b.y); r.u[6] = f2bf(b.z); r.u[7] = f2bf(b.w);
  return r.v;
}

// prep: K f32 [b][k][d] -> Kbf bf16 (same layout); V f32 [b][k][d] -> VT bf16 [b][d][k].
// (Validated: R2's prep produced output bit-identical to the no-ws R3 kernel.)
__global__ __launch_bounds__(256) void prep(const float* __restrict__ K,
                                            const float* __restrict__ V,
                                            ushort* __restrict__ Kbf,
                                            ushort* __restrict__ VT) {
  const int b = blockIdx.x, kt = blockIdx.y, t = threadIdx.x;

  const float* Ks = K + ((size_t)b * LL + kt * 64) * DD;
  ushort* Kd = Kbf + ((size_t)b * LL + kt * 64) * DD;
#pragma unroll
  for (int i = 0; i < 4; ++i) {
    int e = (i * 256 + t) * 4;
    float4 v = *(const float4*)(Ks + e);
    union { ushort u[4]; uint2 q; } p;
    p.u[0] = f2bf(v.x); p.u[1] = f2bf(v.y); p.u[2] = f2bf(v.z); p.u[3] = f2bf(v.w);
    *(uint2*)(Kd + e) = p.q;
  }

  __shared__ ushort T[64][72];
  const float* Vb = V + ((size_t)b * LL + kt * 64) * DD;
#pragma unroll
  for (int i = 0; i < 4; ++i) {
    int kr = (t >> 4) + i * 16;
    int d0 = (t & 15) * 4;
    float4 v = *(const float4*)(Vb + kr * DD + d0);
    T[d0 + 0][kr] = f2bf(v.x);
    T[d0 + 1][kr] = f2bf(v.y);
    T[d0 + 2][kr] = f2bf(v.z);
    T[d0 + 3][kr] = f2bf(v.w);
  }
  __syncthreads();
  ushort* VTb = VT + (size_t)b * DD * LL + kt * 64;
#pragma unroll
  for (int i = 0; i < 2; ++i) {
    int d = (t >> 3) + i * 32;
    int s8 = (t & 7) * 8;
    *(uint4*)(VTb + (size_t)d * LL + s8) = *(const uint4*)(&T[d][s8]);
  }
}

// Fused attention. Block: 4 waves, one batch b, 16 query rows.
// Phase 1: waves split keys 4x256; B-frags direct bf16 loads from Kbf.
// Phase 2: wave wv owns d-cols [wv*16,wv*16+16); A from LDS Ws, B from global VT.
#define WSTR 1028  // Ws row stride in ushorts: 514 dwords ≡ 2 (mod 8) -> 2 lanes/bank writes
__global__ __launch_bounds__(256) void attn(
    const float* __restrict__ Q, const ushort* __restrict__ Kbf,
    const int* __restrict__ vlen, const ushort* __restrict__ VTg,
    float* __restrict__ outS, float* __restrict__ outW) {
  __shared__ __align__(16) ushort Ws[16][WSTR];  // 32,896 B
  __shared__ float redm[4][16];
  __shared__ float reds[4][16];

  const int b = blockIdx.x >> 6;
  const int q0 = (blockIdx.x & 63) << 4;
  const int tid = threadIdx.x;
  const int wv = tid >> 6, lane = tid & 63;
  const int quad = lane >> 4, n16 = lane & 15;
  const int vl = vlen[b];

  // A-frags from Q (f32 -> bf16): A[m=n16][k=quad*8+j], second mfma k+32
  const float* Qp = Q + (size_t)(b * LL + q0 + n16) * DD + quad * 8;
  bf16x8 a0 = pack8(*(const float4*)Qp, *(const float4*)(Qp + 4));
  bf16x8 a1 = pack8(*(const float4*)(Qp + 32), *(const float4*)(Qp + 36));

  const ushort* Kb = Kbf + (size_t)b * LL * DD;
  const int kb = wv * 256 + n16;

  // ---- Phase 1: scores, 16 key-tiles of 16 per wave ----
  f32x4 acc[16];
#pragma unroll
  for (int t = 0; t < 16; ++t) {
    const ushort* Kp = Kb + (size_t)(kb + t * 16) * DD + quad * 8;
    f32x4 c = {0.f, 0.f, 0.f, 0.f};
    c = __builtin_amdgcn_mfma_f32_16x16x32_bf16(a0, *(const bf16x8*)Kp, c, 0, 0, 0);
    c = __builtin_amdgcn_mfma_f32_16x16x32_bf16(a1, *(const bf16x8*)(Kp + 32), c, 0, 0, 0);
    acc[t] = c;
  }

  // scale + mask + row max (lane holds rows quad*4+r, col kb+t*16)
  float pm[4] = {-3.0e38f, -3.0e38f, -3.0e38f, -3.0e38f};
#pragma unroll
  for (int t = 0; t < 16; ++t) {
    const bool valid = (kb + t * 16) < vl;
#pragma unroll
    for (int r = 0; r < 4; ++r) {
      float v = valid ? acc[t][r] * 0.125f : -1.0e6f;
      acc[t][r] = v;
      pm[r] = fmaxf(pm[r], v);
    }
  }
#pragma unroll
  for (int off = 1; off < 16; off <<= 1) {
#pragma unroll
    for (int r = 0; r < 4; ++r) pm[r] = fmaxf(pm[r], __shfl_xor(pm[r], off));
  }
  if (n16 == 0) {
#pragma unroll
    for (int r = 0; r < 4; ++r) redm[wv][quad * 4 + r] = pm[r];
  }
  __syncthreads();
  float gm[4];
#pragma unroll
  for (int r = 0; r < 4; ++r) {
    int row = quad * 4 + r;
    gm[r] = fmaxf(fmaxf(redm[0][row], redm[1][row]),
                  fmaxf(redm[2][row], redm[3][row]));
  }
  float ps[4] = {0.f, 0.f, 0.f, 0.f};
#pragma unroll
  for (int t = 0; t < 16; ++t) {
#pragma unroll
    for (int r = 0; r < 4; ++r) {
      float e = __expf(acc[t][r] - gm[r]);
      acc[t][r] = e;
      ps[r] += e;
    }
  }
#pragma unroll
  for (int off = 1; off < 16; off <<= 1) {
#pragma unroll
    for (int r = 0; r < 4; ++r) ps[r] += __shfl_xor(ps[r], off);
  }
  if (n16 == 0) {
#pragma unroll
    for (int r = 0; r < 4; ++r) reds[wv][quad * 4 + r] = ps[r];
  }
  __syncthreads();
  float inv[4];
#pragma unroll
  for (int r = 0; r < 4; ++r) {
    int row = quad * 4 + r;
    inv[r] = 1.0f / (reds[0][row] + reds[1][row] + reds[2][row] + reds[3][row]);
  }

  // W -> LDS bf16 (conflict-free: 32 banks, 2 lanes/bank per store)
#pragma unroll
  for (int t = 0; t < 16; ++t) {
#pragma unroll
    for (int r = 0; r < 4; ++r)
      Ws[quad * 4 + r][kb + t * 16] = f2bf(acc[t][r] * inv[r]);
  }
  __syncthreads();

  // ---- attn_w f32 store from Ws (bf16->f32 shift), fully coalesced float4 ----
  {
    float* dstW = outW + (size_t)b * LL * LL + (size_t)q0 * LL;
#pragma unroll
    for (int i = 0; i < 16; ++i) {
      int j = i * 256 + tid;            // float4 index 0..4095
      int row = j >> 8, c4 = j & 255;   // 256 float4s per 1024-wide row
      uint2 u = *(const uint2*)(&Ws[row][c4 * 4]);
      union { unsigned q[4]; float4 v; } o;
      o.q[0] = u.x << 16; o.q[1] = u.x & 0xffff0000u;
      o.q[2] = u.y << 16; o.q[3] = u.y & 0xffff0000u;
      *(float4*)(dstW + (size_t)row * LL + c4 * 4) = o.v;
    }
  }

  // ---- Phase 2: O = W * V. A from Ws, B from global VT (L2-resident). ----
  f32x4 o = {0.f, 0.f, 0.f, 0.f};
  const ushort* VTb = VTg + (size_t)b * DD * LL + (size_t)(wv * 16 + n16) * LL;
#pragma unroll
  for (int hs = 0; hs < 32; ++hs) {
    int k0 = hs * 32 + quad * 8;
    bf16x8 af = *(const bf16x8*)(&Ws[n16][k0]);
    bf16x8 bv = *(const bf16x8*)(VTb + k0);
    o = __builtin_amdgcn_mfma_f32_16x16x32_bf16(af, bv, o, 0, 0, 0);
  }
#pragma unroll
  for (int r = 0; r < 4; ++r) {
    outS[(size_t)(b * LL + q0 + quad * 4 + r) * DD + wv * 16 + n16] = o[r];
  }
}

extern "C" void kernel_launch(void* const* d_in, const int* in_sizes, int n_in,
                              void* d_out, int out_size, void* d_ws, size_t ws_size,
                              hipStream_t stream) {
  const float* Q = (const float*)d_in[0];
  const float* K = (const float*)d_in[1];
  const float* V = (const float*)d_in[2];
  const int* vl = (const int*)d_in[3];
  float* outS = (float*)d_out;                 // attn_score [32,1024,64] f32
  float* outW = outS + (size_t)BB * LL * DD;   // attn_w     [32,1024,1024] f32
  ushort* VT = (ushort*)d_ws;                  // 4 MB bf16 V^T
  ushort* Kbf = VT + (size_t)BB * DD * LL;     // 4 MB bf16 K

  prep<<<dim3(BB, 16), 256, 0, stream>>>(K, V, Kbf, VT);
  attn<<<dim3(BB * 64), 256, 0, stream>>>(Q, Kbf, vl, VT, outS, outW);
}

// Round 7
// 212.800 us; speedup vs baseline: 1.3490x; 1.0266x over previous
//
#include <hip/hip_runtime.h>

#define BB 32
#define LL 1024
#define DD 64

typedef short bf16x8 __attribute__((ext_vector_type(8)));
typedef float f32x4 __attribute__((ext_vector_type(4)));

static __device__ __forceinline__ ushort f2bf(float x) {
  union { float f; unsigned u; } c; c.f = x;
  unsigned r = c.u + 0x7FFF + ((c.u >> 16) & 1);
  return (ushort)(r >> 16);
}

static __device__ __forceinline__ bf16x8 pack8(float4 a, float4 b) {
  union { ushort u[8]; bf16x8 v; } r;
  r.u[0] = f2bf(a.x); r.u[1] = f2bf(a.y); r.u[2] = f2bf(a.z); r.u[3] = f2bf(a.w);
  r.u[4] = f2bf(b.x); r.u[5] = f2bf(b.y); r.u[6] = f2bf(b.z); r.u[7] = f2bf(b.w);
  return r.v;
}

// prep: K f32 [b][k][d] -> Kbf bf16 (same layout); V f32 [b][k][d] -> VT bf16 [b][d][k].
__global__ __launch_bounds__(256) void prep(const float* __restrict__ K,
                                            const float* __restrict__ V,
                                            ushort* __restrict__ Kbf,
                                            ushort* __restrict__ VT) {
  const int b = blockIdx.x, kt = blockIdx.y, t = threadIdx.x;

  const float* Ks = K + ((size_t)b * LL + kt * 64) * DD;
  ushort* Kd = Kbf + ((size_t)b * LL + kt * 64) * DD;
#pragma unroll
  for (int i = 0; i < 4; ++i) {
    int e = (i * 256 + t) * 4;
    float4 v = *(const float4*)(Ks + e);
    union { ushort u[4]; uint2 q; } p;
    p.u[0] = f2bf(v.x); p.u[1] = f2bf(v.y); p.u[2] = f2bf(v.z); p.u[3] = f2bf(v.w);
    *(uint2*)(Kd + e) = p.q;
  }

  __shared__ ushort T[64][72];
  const float* Vb = V + ((size_t)b * LL + kt * 64) * DD;
#pragma unroll
  for (int i = 0; i < 4; ++i) {
    int kr = (t >> 4) + i * 16;
    int d0 = (t & 15) * 4;
    float4 v = *(const float4*)(Vb + kr * DD + d0);
    T[d0 + 0][kr] = f2bf(v.x);
    T[d0 + 1][kr] = f2bf(v.y);
    T[d0 + 2][kr] = f2bf(v.z);
    T[d0 + 3][kr] = f2bf(v.w);
  }
  __syncthreads();
  ushort* VTb = VT + (size_t)b * DD * LL + kt * 64;
#pragma unroll
  for (int i = 0; i < 2; ++i) {
    int d = (t >> 3) + i * 32;
    int s8 = (t & 7) * 8;
    *(uint4*)(VTb + (size_t)d * LL + s8) = *(const uint4*)(&T[d][s8]);
  }
}

// Fused attention. Block: 4 waves, one batch b, 16 query rows.
// Stores of attn_w go LAST (vmcnt is in-order: loads issued after stores would
// otherwise wait on the 64 KB/block write drain).
#define WSTR 1028  // Ws row stride (ushorts): writes land 2 lanes/bank (free)
__global__ __launch_bounds__(256, 4) void attn(
    const float* __restrict__ Q, const ushort* __restrict__ Kbf,
    const int* __restrict__ vlen, const ushort* __restrict__ VTg,
    float* __restrict__ outS, float* __restrict__ outW) {
  __shared__ __align__(16) ushort Ws[16][WSTR];  // 32,896 B
  __shared__ float redm[4][16];
  __shared__ float reds[4][16];

  const int b = blockIdx.x >> 6;
  const int q0 = (blockIdx.x & 63) << 4;
  const int tid = threadIdx.x;
  const int wv = tid >> 6, lane = tid & 63;
  const int quad = lane >> 4, n16 = lane & 15;
  const int vl = vlen[b];

  // A-frags from Q (f32 -> bf16): A[m=n16][k=quad*8+j], second mfma k+32
  const float* Qp = Q + (size_t)(b * LL + q0 + n16) * DD + quad * 8;
  bf16x8 a0 = pack8(*(const float4*)Qp, *(const float4*)(Qp + 4));
  bf16x8 a1 = pack8(*(const float4*)(Qp + 32), *(const float4*)(Qp + 36));

  const ushort* Kb = Kbf + (size_t)b * LL * DD;
  const int kb = wv * 256 + n16;

  // ---- Phase 1: scores, 16 key-tiles of 16 per wave ----
  f32x4 acc[16];
#pragma unroll
  for (int t = 0; t < 16; ++t) {
    const ushort* Kp = Kb + (size_t)(kb + t * 16) * DD + quad * 8;
    f32x4 c = {0.f, 0.f, 0.f, 0.f};
    c = __builtin_amdgcn_mfma_f32_16x16x32_bf16(a0, *(const bf16x8*)Kp, c, 0, 0, 0);
    c = __builtin_amdgcn_mfma_f32_16x16x32_bf16(a1, *(const bf16x8*)(Kp + 32), c, 0, 0, 0);
    acc[t] = c;
  }

  // scale + mask + row max (lane holds rows quad*4+r, col kb+t*16)
  float pm[4] = {-3.0e38f, -3.0e38f, -3.0e38f, -3.0e38f};
#pragma unroll
  for (int t = 0; t < 16; ++t) {
    const bool valid = (kb + t * 16) < vl;
#pragma unroll
    for (int r = 0; r < 4; ++r) {
      float v = valid ? acc[t][r] * 0.125f : -1.0e6f;
      acc[t][r] = v;
      pm[r] = fmaxf(pm[r], v);
    }
  }
#pragma unroll
  for (int off = 1; off < 16; off <<= 1) {
#pragma unroll
    for (int r = 0; r < 4; ++r) pm[r] = fmaxf(pm[r], __shfl_xor(pm[r], off));
  }
  if (n16 == 0) {
#pragma unroll
    for (int r = 0; r < 4; ++r) redm[wv][quad * 4 + r] = pm[r];
  }
  __syncthreads();
  float gm[4];
#pragma unroll
  for (int r = 0; r < 4; ++r) {
    int row = quad * 4 + r;
    gm[r] = fmaxf(fmaxf(redm[0][row], redm[1][row]),
                  fmaxf(redm[2][row], redm[3][row]));
  }
  float ps[4] = {0.f, 0.f, 0.f, 0.f};
#pragma unroll
  for (int t = 0; t < 16; ++t) {
#pragma unroll
    for (int r = 0; r < 4; ++r) {
      float e = __expf(acc[t][r] - gm[r]);
      acc[t][r] = e;
      ps[r] += e;
    }
  }
#pragma unroll
  for (int off = 1; off < 16; off <<= 1) {
#pragma unroll
    for (int r = 0; r < 4; ++r) ps[r] += __shfl_xor(ps[r], off);
  }
  if (n16 == 0) {
#pragma unroll
    for (int r = 0; r < 4; ++r) reds[wv][quad * 4 + r] = ps[r];
  }
  __syncthreads();
  float inv[4];
#pragma unroll
  for (int r = 0; r < 4; ++r) {
    int row = quad * 4 + r;
    inv[r] = 1.0f / (reds[0][row] + reds[1][row] + reds[2][row] + reds[3][row]);
  }

  // W -> LDS bf16 (conflict-free)
#pragma unroll
  for (int t = 0; t < 16; ++t) {
#pragma unroll
    for (int r = 0; r < 4; ++r)
      Ws[quad * 4 + r][kb + t * 16] = f2bf(acc[t][r] * inv[r]);
  }
  __syncthreads();

  // ---- Phase 2 FIRST (no stores ahead of these loads in the vmcnt queue).
  //      O = W * V: A from Ws, B from global VT; 4 groups of 8, loads batched. ----
  f32x4 o = {0.f, 0.f, 0.f, 0.f};
  const ushort* VTb = VTg + (size_t)b * DD * LL + (size_t)(wv * 16 + n16) * LL;
#pragma unroll
  for (int g = 0; g < 4; ++g) {
    bf16x8 af[8], bv[8];
#pragma unroll
    for (int i = 0; i < 8; ++i) {
      int k0 = (g * 8 + i) * 32 + quad * 8;
      bv[i] = *(const bf16x8*)(VTb + k0);
      af[i] = *(const bf16x8*)(&Ws[n16][k0]);
    }
#pragma unroll
    for (int i = 0; i < 8; ++i)
      o = __builtin_amdgcn_mfma_f32_16x16x32_bf16(af[i], bv[i], o, 0, 0, 0);
  }
#pragma unroll
  for (int r = 0; r < 4; ++r) {
    outS[(size_t)(b * LL + q0 + quad * 4 + r) * DD + wv * 16 + n16] = o[r];
  }

  // ---- attn_w f32 store LAST (fire-and-forget drain) ----
  {
    float* dstW = outW + (size_t)b * LL * LL + (size_t)q0 * LL;
#pragma unroll
    for (int i = 0; i < 16; ++i) {
      int j = i * 256 + tid;            // float4 index 0..4095
      int row = j >> 8, c4 = j & 255;
      uint2 u = *(const uint2*)(&Ws[row][c4 * 4]);
      union { unsigned q[4]; float4 v; } ov;
      ov.q[0] = u.x << 16; ov.q[1] = u.x & 0xffff0000u;
      ov.q[2] = u.y << 16; ov.q[3] = u.y & 0xffff0000u;
      *(float4*)(dstW + (size_t)row * LL + c4 * 4) = ov.v;
    }
  }
}

extern "C" void kernel_launch(void* const* d_in, const int* in_sizes, int n_in,
                              void* d_out, int out_size, void* d_ws, size_t ws_size,
                              hipStream_t stream) {
  const float* Q = (const float*)d_in[0];
  const float* K = (const float*)d_in[1];
  const float* V = (const float*)d_in[2];
  const int* vl = (const int*)d_in[3];
  float* outS = (float*)d_out;                 // attn_score [32,1024,64] f32
  float* outW = outS + (size_t)BB * LL * DD;   // attn_w     [32,1024,1024] f32
  ushort* VT = (ushort*)d_ws;                  // 4 MB bf16 V^T
  ushort* Kbf = VT + (size_t)BB * DD * LL;     // 4 MB bf16 K

  prep<<<dim3(BB, 16), 256, 0, stream>>>(K, V, Kbf, VT);
  attn<<<dim3(BB * 64), 256, 0, stream>>>(Q, Kbf, vl, VT, outS, outW);
}